// Round 1
// baseline (1248.796 us; speedup 1.0000x reference)
//
#include <hip/hip_runtime.h>
#include <hip/hip_bf16.h>

typedef _Float16 f16;
typedef f16 f16x8 __attribute__((ext_vector_type(8)));
typedef f16 f16x4 __attribute__((ext_vector_type(4)));
typedef float f32x4 __attribute__((ext_vector_type(4)));

static constexpr int NDATA = 50000;
static constexpr int DF    = 3072;
static constexpr int BP    = 256;
static constexpr int NLD1  = 50048;   // S rows   (782*64)
static constexpr int NLD2  = 50176;   // W cols   (16*3136)
static constexpr int GRED  = 391;     // 391*128 = 50048
static constexpr int NCH   = 16;      // split-K chunks in PV
static constexpr int CHN   = 3136;    // n per chunk (98*32)
static constexpr int KS_PV = 98;

// workspace offsets (bytes), all 16B aligned
static constexpr size_t OFF_S  = 0;            // S : 50048*256*4   = 51249152
static constexpr size_t OFF_W  = 51249152;     // W : 256*50176*2   = 25690112
static constexpr size_t OFF_XH = 76939264;     // xh: 256*3072*2    = 1572864
static constexpr size_t OFF_MP = 78512128;     // Mp: 391*256*4     = 400384
static constexpr size_t OFF_LP = 78912512;     // Lp: 391*256*4     = 400384
static constexpr size_t OFF_M  = 79312896;     // M : 256*4 (+pad)
static constexpr size_t OFF_L  = 79313920;     // L : 256*4 (+pad)
static constexpr size_t OFF_P  = 79314944;     // P : 16*786432*4   = 50331648  -> end 129646592

// ---------------- K1: x -> fp16 ----------------
__global__ void k_prep_x(const float* __restrict__ x, f16* __restrict__ xh) {
  int i = blockIdx.x * 256 + threadIdx.x;          // float4 index, 196608 total
  f32x4 v = ((const f32x4*)x)[i];
  f16x4 h;
  h[0] = (f16)v[0]; h[1] = (f16)v[1]; h[2] = (f16)v[2]; h[3] = (f16)v[3];
  ((f16x4*)xh)[i] = h;
}

// ---------------- K2: S[n][b] = (2*d.x - |d|^2) / (2 sigma^2) ----------------
// block: 256 thr (4 waves), tile 64 n x 256 b. No LDS: A (data, fp32->f16 in reg)
// and B (x_f16, L2-resident) fragments loaded straight from global.
__global__ __launch_bounds__(256) void k_qk(const float* __restrict__ data,
                                            const f16* __restrict__ xh,
                                            const float* __restrict__ sigma,
                                            float* __restrict__ S) {
  const int tid = threadIdx.x;
  const int wid = tid >> 6, lane = tid & 63;
  const int l15 = lane & 15, kg = lane >> 4;
  const int n0 = blockIdx.x * 64;
  const int rowA = n0 + wid * 16 + l15;
  const int rAc = rowA < NDATA ? rowA : NDATA - 1;
  const float* ap = data + (size_t)rAc * DF + kg * 8;
  const f16*   bp = xh + (size_t)l15 * DF + kg * 8;

  f32x4 acc[16] = {};
  float sq = 0.f;

  for (int k0 = 0; k0 < DF; k0 += 32) {
    f32x4 a0 = *(const f32x4*)(ap + k0);
    f32x4 a1 = *(const f32x4*)(ap + k0 + 4);
    f16x8 af;
#pragma unroll
    for (int j = 0; j < 4; ++j) { af[j] = (f16)a0[j]; af[4 + j] = (f16)a1[j]; }
#pragma unroll
    for (int j = 0; j < 4; ++j) { sq = fmaf(a0[j], a0[j], sq); sq = fmaf(a1[j], a1[j], sq); }
#pragma unroll
    for (int g = 0; g < 4; ++g) {
      f16x8 bf[4];
#pragma unroll
      for (int c = 0; c < 4; ++c)
        bf[c] = *(const f16x8*)(bp + (size_t)(g * 4 + c) * 16 * DF + k0);
#pragma unroll
      for (int c = 0; c < 4; ++c)
        acc[g * 4 + c] = __builtin_amdgcn_mfma_f32_16x16x32_f16(af, bf[c], acc[g * 4 + c], 0, 0, 0);
    }
  }
  // reduce |d|^2 across the 4 k-groups; every lane ends with dnorm of row (l&15)
  sq += __shfl_xor(sq, 16);
  sq += __shfl_xor(sq, 32);

  const float sg  = sigma[0];
  const float inv = 0.5f / (sg * sg);
#pragma unroll
  for (int r = 0; r < 4; ++r) {
    const int row = n0 + wid * 16 + kg * 4 + r;      // C/D: row=(l>>4)*4+reg
    const float dn = __shfl(sq, kg * 4 + r);
    const bool ok = row < NDATA;
    float* Sp = S + (size_t)row * BP + l15;          // col = l&15
#pragma unroll
    for (int c = 0; c < 16; ++c) {
      float sv = ok ? (2.f * acc[c][r] - dn) * inv : -1e30f;
      Sp[c * 16] = sv;
    }
  }
}

// ---------------- K3: per-column online (max, sumexp) partials ----------------
__global__ void k_red(const float* __restrict__ S, float* __restrict__ Mp,
                      float* __restrict__ Lp) {
  const int tid = threadIdx.x;
  const int g = blockIdx.x;
  const float* p = S + (size_t)g * 128 * BP + tid;
  float m = -1e38f, l = 0.f;
  for (int i = 0; i < 128; ++i) {
    float s = p[(size_t)i * BP];
    if (s > m) { l = l * __expf(m - s) + 1.f; m = s; }
    else       { l += __expf(s - m); }
  }
  Mp[g * BP + tid] = m;
  Lp[g * BP + tid] = l;
}

// ---------------- K4: combine partials -> M[b], L[b] ----------------
__global__ void k_comb(const float* __restrict__ Mp, const float* __restrict__ Lp,
                       float* __restrict__ M, float* __restrict__ L) {
  const int tid = threadIdx.x;
  float m = -1e38f, l = 0.f;
  for (int g = 0; g < GRED; ++g) {
    float m2 = Mp[g * BP + tid], l2 = Lp[g * BP + tid];
    if (m2 > m) { l = l * __expf(m - m2) + l2; m = m2; }
    else        { l += l2 * __expf(m2 - m); }
  }
  M[tid] = m;
  L[tid] = l;
}

// ---------------- K5: W[b][n] = exp(S - M_b) as fp16 (transposed layout) ----------------
__global__ void k_wfin(const float* __restrict__ S, const float* __restrict__ M,
                       f16* __restrict__ W) {
  const int tid = threadIdx.x;
  const int n0 = blockIdx.x * 64;
  const float mb = M[tid];
  f16* wp = W + (size_t)tid * NLD2 + n0;
#pragma unroll
  for (int q = 0; q < 8; ++q) {
    f16x8 w8;
#pragma unroll
    for (int j = 0; j < 8; ++j) {
      int n = n0 + q * 8 + j;
      float s = (n < NLD1) ? S[(size_t)n * BP + tid] : -1e30f;  // coalesced across tid
      w8[j] = (f16)__expf(s - mb);
    }
    *(f16x8*)(wp + q * 8) = w8;
  }
}

// ---------------- K6: eps partials = W @ data (split-K over n) ----------------
// block: 512 thr (8 waves), tile 256 b x 128 d, K-step 32 n.
// A = W (k-contiguous, direct global). B = data (fp32 -> f16, LDS transpose w/ XOR swizzle).
__global__ __launch_bounds__(512) void k_pv(const float* __restrict__ data,
                                            const f16* __restrict__ W,
                                            float* __restrict__ part) {
  __shared__ f16 T[2][128 * 40];
  const int tid = threadIdx.x;
  const int wid = tid >> 6, lane = tid & 63;
  const int l15 = lane & 15, kg = lane >> 4;
  const int chunk = blockIdx.x & (NCH - 1);   // bid%16: chunks c,c+8 share XCD c%8
  const int dt = blockIdx.x >> 4;             // 0..23
  const int d0 = dt * 128;
  const int nstart = chunk * CHN;
  const int nl = tid >> 4, dl = (tid & 15) * 8;  // staging: 32 n-rows x 16 thr

  f32x4 acc[2][8] = {};

  const f16* wp0 = W + (size_t)((wid * 2 + 0) * 16 + l15) * NLD2 + kg * 8;
  const f16* wp1 = W + (size_t)((wid * 2 + 1) * 16 + l15) * NLD2 + kg * 8;

  f32x4 g0, g1;
  auto gload = [&](int ks) {
    int row = nstart + ks * 32 + nl;
    int rc = row < NDATA ? row : NDATA - 1;     // tail rows have W==0
    const float* gp = data + (size_t)rc * DF + d0 + dl;
    g0 = *(const f32x4*)gp;
    g1 = *(const f32x4*)(gp + 4);
  };
  auto twrite = [&](int buf) {
#pragma unroll
    for (int j = 0; j < 8; ++j) {
      float v = (j < 4) ? g0[j] : g1[j - 4];
      int d = dl + j;
      int pn = nl ^ (((d >> 3) & 3) << 3);      // bank swizzle, keeps 8-n units contiguous
      T[buf][d * 40 + pn] = (f16)v;
    }
  };

  gload(0);
  twrite(0);
  __syncthreads();

  for (int ks = 0; ks < KS_PV; ++ks) {
    const int cur = ks & 1;
    if (ks + 1 < KS_PV) gload(ks + 1);
    const int nk = nstart + ks * 32;
    f16x8 af0 = *(const f16x8*)(wp0 + nk);
    f16x8 af1 = *(const f16x8*)(wp1 + nk);
    f16x8 bf[8];
#pragma unroll
    for (int c = 0; c < 8; ++c) {
      int d = c * 16 + l15;
      int pb = (kg * 8) ^ (((d >> 3) & 3) << 3);
      bf[c] = *(const f16x8*)(&T[cur][d * 40 + pb]);
    }
#pragma unroll
    for (int c = 0; c < 8; ++c) {
      acc[0][c] = __builtin_amdgcn_mfma_f32_16x16x32_f16(af0, bf[c], acc[0][c], 0, 0, 0);
      acc[1][c] = __builtin_amdgcn_mfma_f32_16x16x32_f16(af1, bf[c], acc[1][c], 0, 0, 0);
    }
    if (ks + 1 < KS_PV) twrite(cur ^ 1);
    __syncthreads();
  }

  float* pp = part + (size_t)chunk * (BP * DF);
#pragma unroll
  for (int i = 0; i < 2; ++i)
#pragma unroll
    for (int c = 0; c < 8; ++c)
#pragma unroll
      for (int r = 0; r < 4; ++r) {
        int b = (wid * 2 + i) * 16 + kg * 4 + r;
        int d = d0 + c * 16 + l15;
        pp[(size_t)b * DF + d] = acc[i][c][r];
      }
}

// ---------------- K7: out = (x - (sum partials)/L) / sigma ----------------
__global__ void k_final(const float* __restrict__ x, const float* __restrict__ sigma,
                        const float* __restrict__ part, const float* __restrict__ L,
                        float* __restrict__ out) {
  int i = blockIdx.x * 256 + threadIdx.x;   // float4 index
  int b = (i * 4) / DF;
  f32x4 s = {};
#pragma unroll
  for (int c = 0; c < NCH; ++c) s += ((const f32x4*)(part + (size_t)c * BP * DF))[i];
  f32x4 xv = ((const f32x4*)x)[i];
  float invL = 1.f / L[b];
  float sg = sigma[0];
  float invsg = 1.f / sg;
  f32x4 r;
#pragma unroll
  for (int j = 0; j < 4; ++j) r[j] = (xv[j] - s[j] * invL) * invsg;
  ((f32x4*)out)[i] = r;
}

extern "C" void kernel_launch(void* const* d_in, const int* in_sizes, int n_in,
                              void* d_out, int out_size, void* d_ws, size_t ws_size,
                              hipStream_t stream) {
  const float* x     = (const float*)d_in[0];
  const float* sigma = (const float*)d_in[1];
  const float* data  = (const float*)d_in[2];
  float* out = (float*)d_out;
  char* ws = (char*)d_ws;

  float* S  = (float*)(ws + OFF_S);
  f16*   W  = (f16*)(ws + OFF_W);
  f16*   xh = (f16*)(ws + OFF_XH);
  float* Mp = (float*)(ws + OFF_MP);
  float* Lp = (float*)(ws + OFF_LP);
  float* M  = (float*)(ws + OFF_M);
  float* L  = (float*)(ws + OFF_L);
  float* P  = (float*)(ws + OFF_P);

  k_prep_x<<<768, 256, 0, stream>>>(x, xh);
  k_qk<<<782, 256, 0, stream>>>(data, xh, sigma, S);
  k_red<<<GRED, 256, 0, stream>>>(S, Mp, Lp);
  k_comb<<<1, 256, 0, stream>>>(Mp, Lp, M, L);
  k_wfin<<<784, 256, 0, stream>>>(S, M, W);
  k_pv<<<24 * NCH, 512, 0, stream>>>(data, W, P);
  k_final<<<768, 256, 0, stream>>>(x, sigma, P, L, out);
}

// Round 2
// 686.617 us; speedup vs baseline: 1.8188x; 1.8188x over previous
//
#include <hip/hip_runtime.h>
#include <hip/hip_bf16.h>

typedef _Float16 f16;
typedef f16 f16x8 __attribute__((ext_vector_type(8)));
typedef f16 f16x4 __attribute__((ext_vector_type(4)));
typedef float f32x4 __attribute__((ext_vector_type(4)));

static constexpr int NDATA = 50000;
static constexpr int DF    = 3072;
static constexpr int BP    = 256;
static constexpr int NLD1  = 50048;   // S rows   (782*64)
static constexpr int NLD2  = 50176;   // W cols   (16*3136)
static constexpr int GRED  = 391;     // 391*128 = 50048
static constexpr int NCH   = 16;      // split-K chunks in PV
static constexpr int CHN   = 3136;    // n per chunk (98*32)
static constexpr int KS_PV = 98;

// workspace offsets (bytes), all 16B aligned
static constexpr size_t OFF_S  = 0;            // S : 50048*256*4   = 51249152
static constexpr size_t OFF_W  = 51249152;     // W : 256*50176*2   = 25690112
static constexpr size_t OFF_XH = 76939264;     // xh: 256*3072*2    = 1572864
static constexpr size_t OFF_MP = 78512128;     // Mp: 391*256*4     = 400384
static constexpr size_t OFF_LP = 78912512;     // Lp: 391*256*4     = 400384
static constexpr size_t OFF_M  = 79312896;     // M : 256*4 (+pad)
static constexpr size_t OFF_L  = 79313920;     // L : 256*4 (+pad)
static constexpr size_t OFF_P  = 79314944;     // P : 16*786432*4   = 50331648  -> end 129646592

// ---------------- K1: x -> fp16 ----------------
__global__ void k_prep_x(const float* __restrict__ x, f16* __restrict__ xh) {
  int i = blockIdx.x * 256 + threadIdx.x;          // float4 index, 196608 total
  f32x4 v = ((const f32x4*)x)[i];
  f16x4 h;
  h[0] = (f16)v[0]; h[1] = (f16)v[1]; h[2] = (f16)v[2]; h[3] = (f16)v[3];
  ((f16x4*)xh)[i] = h;
}

// ---------------- K2: S[n][b] = (2*d.x - |d|^2) / (2 sigma^2) ----------------
// LDS-staged double-buffered MFMA GEMM. 512 thr = 8 waves (4 n-groups x 2 b-halves),
// tile 64 n x 256 b, K-step 32. A = data (fp32->f16 in reg, |d|^2 fused),
// B = xh. LDS rows padded to 40 f16 (80 B, 16B-aligned, conflict-free-ish reads).
static constexpr int QPAD = 40;
__global__ __launch_bounds__(512, 4) void k_qk(const float* __restrict__ data,
                                               const f16* __restrict__ xh,
                                               const float* __restrict__ sigma,
                                               float* __restrict__ S) {
  __shared__ f16 As[2][64 * QPAD];    // 2 x 5120 B
  __shared__ f16 Bs[2][256 * QPAD];   // 2 x 20480 B
  __shared__ float dn_s[64];

  const int tid = threadIdx.x;
  const int wid = tid >> 6, lane = tid & 63;
  const int l15 = lane & 15, kg = lane >> 4;
  const int wr = wid >> 1, wb = wid & 1;
  const int n0 = blockIdx.x * 64;

  // A staging: thread -> (row = tid>>3, 4 floats at (tid&7)*4)
  const int arow = tid >> 3;
  const int ak4  = (tid & 7) * 4;
  const int ar_g = n0 + arow;
  const int ar_c = ar_g < NDATA ? ar_g : NDATA - 1;
  const float* ap = data + (size_t)ar_c * DF + ak4;

  // B staging: thread -> rows (tid>>2) and (tid>>2)+128, 8 f16 at (tid&3)*8
  const int brow = tid >> 2;
  const int bk8  = (tid & 3) * 8;
  const f16* bp0 = xh + (size_t)brow * DF + bk8;
  const f16* bp1 = xh + (size_t)(brow + 128) * DF + bk8;

  f32x4 acc[8] = {};
  float sq = 0.f;
  f32x4 ga;
  f16x8 gb0, gb1;

  auto gload = [&](int k0) {
    ga  = *(const f32x4*)(ap + k0);
    gb0 = *(const f16x8*)(bp0 + k0);
    gb1 = *(const f16x8*)(bp1 + k0);
  };
  auto swrite = [&](int buf) {
    f16x4 h;
#pragma unroll
    for (int j = 0; j < 4; ++j) {
      h[j] = (f16)ga[j];
      sq = fmaf(ga[j], ga[j], sq);
    }
    *(f16x4*)(&As[buf][arow * QPAD + ak4]) = h;
    *(f16x8*)(&Bs[buf][brow * QPAD + bk8]) = gb0;
    *(f16x8*)(&Bs[buf][(brow + 128) * QPAD + bk8]) = gb1;
  };

  gload(0);
  swrite(0);
  __syncthreads();

  for (int ks = 0; ks < 96; ++ks) {
    const int cur = ks & 1;
    if (ks + 1 < 96) gload((ks + 1) * 32);

    f16x8 af = *(const f16x8*)(&As[cur][(wr * 16 + l15) * QPAD + kg * 8]);
    f16x8 bf[8];
#pragma unroll
    for (int c = 0; c < 8; ++c)
      bf[c] = *(const f16x8*)(&Bs[cur][(wb * 128 + c * 16 + l15) * QPAD + kg * 8]);
#pragma unroll
    for (int c = 0; c < 8; ++c)
      acc[c] = __builtin_amdgcn_mfma_f32_16x16x32_f16(af, bf[c], acc[c], 0, 0, 0);

    if (ks + 1 < 96) swrite(cur ^ 1);
    __syncthreads();
  }

  // |d|^2: reduce the 8 k-slice partials (threads tid with same tid>>3)
  sq += __shfl_xor(sq, 1);
  sq += __shfl_xor(sq, 2);
  sq += __shfl_xor(sq, 4);
  if ((lane & 7) == 0) dn_s[wid * 8 + (lane >> 3)] = sq;
  __syncthreads();

  const float sg  = sigma[0];
  const float inv = 0.5f / (sg * sg);
#pragma unroll
  for (int r = 0; r < 4; ++r) {
    const int trow = wr * 16 + kg * 4 + r;         // C/D: row=(l>>4)*4+reg
    const int row  = n0 + trow;
    const float dn = dn_s[trow];
    const bool ok  = row < NDATA;
    float* Sp = S + (size_t)row * BP + wb * 128 + l15;
#pragma unroll
    for (int c = 0; c < 8; ++c) {
      float sv = ok ? (2.f * acc[c][r] - dn) * inv : -1e30f;
      Sp[c * 16] = sv;
    }
  }
}

// ---------------- K3: per-column online (max, sumexp) partials ----------------
__global__ void k_red(const float* __restrict__ S, float* __restrict__ Mp,
                      float* __restrict__ Lp) {
  const int tid = threadIdx.x;
  const int g = blockIdx.x;
  const float* p = S + (size_t)g * 128 * BP + tid;
  float m = -1e38f, l = 0.f;
  for (int i = 0; i < 128; ++i) {
    float s = p[(size_t)i * BP];
    if (s > m) { l = l * __expf(m - s) + 1.f; m = s; }
    else       { l += __expf(s - m); }
  }
  Mp[g * BP + tid] = m;
  Lp[g * BP + tid] = l;
}

// ---------------- K4: combine partials -> M[b], L[b] ----------------
__global__ void k_comb(const float* __restrict__ Mp, const float* __restrict__ Lp,
                       float* __restrict__ M, float* __restrict__ L) {
  const int tid = threadIdx.x;
  float m = -1e38f, l = 0.f;
  for (int g = 0; g < GRED; ++g) {
    float m2 = Mp[g * BP + tid], l2 = Lp[g * BP + tid];
    if (m2 > m) { l = l * __expf(m - m2) + l2; m = m2; }
    else        { l += l2 * __expf(m2 - m); }
  }
  M[tid] = m;
  L[tid] = l;
}

// ---------------- K5: W[b][n] = exp(S - M_b) as fp16 (transposed layout) ----------------
__global__ void k_wfin(const float* __restrict__ S, const float* __restrict__ M,
                       f16* __restrict__ W) {
  const int tid = threadIdx.x;
  const int n0 = blockIdx.x * 64;
  const float mb = M[tid];
  f16* wp = W + (size_t)tid * NLD2 + n0;
#pragma unroll
  for (int q = 0; q < 8; ++q) {
    f16x8 w8;
#pragma unroll
    for (int j = 0; j < 8; ++j) {
      int n = n0 + q * 8 + j;
      float s = (n < NLD1) ? S[(size_t)n * BP + tid] : -1e30f;  // coalesced across tid
      w8[j] = (f16)__expf(s - mb);
    }
    *(f16x8*)(wp + q * 8) = w8;
  }
}

// ---------------- K6: eps partials = W @ data (split-K over n) ----------------
// block: 512 thr (8 waves), tile 256 b x 128 d, K-step 32 n.
// A = W (k-contiguous, direct global). B = data (fp32 -> f16, LDS transpose w/ XOR swizzle).
__global__ __launch_bounds__(512) void k_pv(const float* __restrict__ data,
                                            const f16* __restrict__ W,
                                            float* __restrict__ part) {
  __shared__ f16 T[2][128 * 40];
  const int tid = threadIdx.x;
  const int wid = tid >> 6, lane = tid & 63;
  const int l15 = lane & 15, kg = lane >> 4;
  const int chunk = blockIdx.x & (NCH - 1);   // bid%16: chunks c,c+8 share XCD c%8
  const int dt = blockIdx.x >> 4;             // 0..23
  const int d0 = dt * 128;
  const int nstart = chunk * CHN;
  const int nl = tid >> 4, dl = (tid & 15) * 8;  // staging: 32 n-rows x 16 thr

  f32x4 acc[2][8] = {};

  const f16* wp0 = W + (size_t)((wid * 2 + 0) * 16 + l15) * NLD2 + kg * 8;
  const f16* wp1 = W + (size_t)((wid * 2 + 1) * 16 + l15) * NLD2 + kg * 8;

  f32x4 g0, g1;
  auto gload = [&](int ks) {
    int row = nstart + ks * 32 + nl;
    int rc = row < NDATA ? row : NDATA - 1;     // tail rows have W==0
    const float* gp = data + (size_t)rc * DF + d0 + dl;
    g0 = *(const f32x4*)gp;
    g1 = *(const f32x4*)(gp + 4);
  };
  auto twrite = [&](int buf) {
#pragma unroll
    for (int j = 0; j < 8; ++j) {
      float v = (j < 4) ? g0[j] : g1[j - 4];
      int d = dl + j;
      int pn = nl ^ (((d >> 3) & 3) << 3);      // bank swizzle, keeps 8-n units contiguous
      T[buf][d * 40 + pn] = (f16)v;
    }
  };

  gload(0);
  twrite(0);
  __syncthreads();

  for (int ks = 0; ks < KS_PV; ++ks) {
    const int cur = ks & 1;
    if (ks + 1 < KS_PV) gload(ks + 1);
    const int nk = nstart + ks * 32;
    f16x8 af0 = *(const f16x8*)(wp0 + nk);
    f16x8 af1 = *(const f16x8*)(wp1 + nk);
    f16x8 bf[8];
#pragma unroll
    for (int c = 0; c < 8; ++c) {
      int d = c * 16 + l15;
      int pb = (kg * 8) ^ (((d >> 3) & 3) << 3);
      bf[c] = *(const f16x8*)(&T[cur][d * 40 + pb]);
    }
#pragma unroll
    for (int c = 0; c < 8; ++c) {
      acc[0][c] = __builtin_amdgcn_mfma_f32_16x16x32_f16(af0, bf[c], acc[0][c], 0, 0, 0);
      acc[1][c] = __builtin_amdgcn_mfma_f32_16x16x32_f16(af1, bf[c], acc[1][c], 0, 0, 0);
    }
    if (ks + 1 < KS_PV) twrite(cur ^ 1);
    __syncthreads();
  }

  float* pp = part + (size_t)chunk * (BP * DF);
#pragma unroll
  for (int i = 0; i < 2; ++i)
#pragma unroll
    for (int c = 0; c < 8; ++c)
#pragma unroll
      for (int r = 0; r < 4; ++r) {
        int b = (wid * 2 + i) * 16 + kg * 4 + r;
        int d = d0 + c * 16 + l15;
        pp[(size_t)b * DF + d] = acc[i][c][r];
      }
}

// ---------------- K7: out = (x - (sum partials)/L) / sigma ----------------
__global__ void k_final(const float* __restrict__ x, const float* __restrict__ sigma,
                        const float* __restrict__ part, const float* __restrict__ L,
                        float* __restrict__ out) {
  int i = blockIdx.x * 256 + threadIdx.x;   // float4 index
  int b = (i * 4) / DF;
  f32x4 s = {};
#pragma unroll
  for (int c = 0; c < NCH; ++c) s += ((const f32x4*)(part + (size_t)c * BP * DF))[i];
  f32x4 xv = ((const f32x4*)x)[i];
  float invL = 1.f / L[b];
  float sg = sigma[0];
  float invsg = 1.f / sg;
  f32x4 r;
#pragma unroll
  for (int j = 0; j < 4; ++j) r[j] = (xv[j] - s[j] * invL) * invsg;
  ((f32x4*)out)[i] = r;
}

extern "C" void kernel_launch(void* const* d_in, const int* in_sizes, int n_in,
                              void* d_out, int out_size, void* d_ws, size_t ws_size,
                              hipStream_t stream) {
  const float* x     = (const float*)d_in[0];
  const float* sigma = (const float*)d_in[1];
  const float* data  = (const float*)d_in[2];
  float* out = (float*)d_out;
  char* ws = (char*)d_ws;

  float* S  = (float*)(ws + OFF_S);
  f16*   W  = (f16*)(ws + OFF_W);
  f16*   xh = (f16*)(ws + OFF_XH);
  float* Mp = (float*)(ws + OFF_MP);
  float* Lp = (float*)(ws + OFF_LP);
  float* M  = (float*)(ws + OFF_M);
  float* L  = (float*)(ws + OFF_L);
  float* P  = (float*)(ws + OFF_P);

  k_prep_x<<<768, 256, 0, stream>>>(x, xh);
  k_qk<<<782, 512, 0, stream>>>(data, xh, sigma, S);
  k_red<<<GRED, 256, 0, stream>>>(S, Mp, Lp);
  k_comb<<<1, 256, 0, stream>>>(Mp, Lp, M, L);
  k_wfin<<<784, 256, 0, stream>>>(S, M, W);
  k_pv<<<24 * NCH, 512, 0, stream>>>(data, W, P);
  k_final<<<768, 256, 0, stream>>>(x, sigma, P, L, out);
}

// Round 3
// 647.453 us; speedup vs baseline: 1.9288x; 1.0605x over previous
//
#include <hip/hip_runtime.h>
#include <hip/hip_bf16.h>

typedef _Float16 f16;
typedef f16 f16x8 __attribute__((ext_vector_type(8)));
typedef f16 f16x4 __attribute__((ext_vector_type(4)));
typedef float f32x4 __attribute__((ext_vector_type(4)));

static constexpr int NDATA = 50000;
static constexpr int DF    = 3072;
static constexpr int BP    = 256;
static constexpr int NLD1  = 50048;   // S rows (782*64)
static constexpr int NLD2  = 51200;   // W cols (800*64), zero-padded past NLD1
static constexpr int NGRP  = 782;     // softmax partial groups (one per k_qk block)
static constexpr int NDT   = 24;      // d-tiles of 128 in k_pv

// workspace offsets (bytes)
static constexpr size_t OFF_S  = 0;            // S : 50048*256*4 = 51249152
static constexpr size_t OFF_W  = 51249152;     // W : 256*51200*2 = 26214400
static constexpr size_t OFF_XH = 77463552;     // xh: 256*3072*2  = 1572864
static constexpr size_t OFF_MP = 79036416;     // Mp: 782*256*4   = 800768
static constexpr size_t OFF_LP = 79837184;     // Lp: 782*256*4   = 800768
static constexpr size_t OFF_M  = 80637952;     // M : 256*4 (+pad)
static constexpr size_t OFF_L  = 80638976;     // L : 256*4 (+pad)
static constexpr size_t OFF_P  = 80640000;     // P : nch * 3145728
static constexpr size_t SLAB   = (size_t)BP * DF * 4;   // 3145728

// ---------------- K1: x -> fp16 ----------------
__global__ void k_prep_x(const float* __restrict__ x, f16* __restrict__ xh) {
  int i = blockIdx.x * 256 + threadIdx.x;          // float4 index, 196608 total
  f32x4 v = ((const f32x4*)x)[i];
  f16x4 h;
  h[0] = (f16)v[0]; h[1] = (f16)v[1]; h[2] = (f16)v[2]; h[3] = (f16)v[3];
  ((f16x4*)xh)[i] = h;
}

// ---------------- K2: S[n][b] = (2*d.x - |d|^2)/(2 sigma^2), + fused per-block (m,l) ----------------
// 512 thr = 8 waves (4 n-groups x 2 b-halves), tile 64n x 256b, K-step 32.
// 2-deep register prefetch pipeline -> LDS double buffer.
static constexpr int QPAD = 40;
__global__ __launch_bounds__(512, 4) void k_qk(const float* __restrict__ data,
                                               const f16* __restrict__ xh,
                                               const float* __restrict__ sigma,
                                               float* __restrict__ S,
                                               float* __restrict__ Mp,
                                               float* __restrict__ Lp) {
  __shared__ f16 As[2][64 * QPAD];    // 2 x 5120 B
  __shared__ f16 Bs[2][256 * QPAD];   // 2 x 20480 B (reused post-loop for (m,l) tree)
  __shared__ float dn_s[64];

  const int tid = threadIdx.x;
  const int wid = tid >> 6, lane = tid & 63;
  const int l15 = lane & 15, kg = lane >> 4;
  const int wr = wid >> 1, wb = wid & 1;
  const int n0 = blockIdx.x * 64;

  // A staging: row = tid>>3, 4 floats at (tid&7)*4
  const int arow = tid >> 3;
  const int ak4  = (tid & 7) * 4;
  const int ar_g = n0 + arow;
  const int ar_c = ar_g < NDATA ? ar_g : NDATA - 1;
  const float* ap = data + (size_t)ar_c * DF + ak4;

  // B staging: rows tid>>2 and +128, 8 f16 at (tid&3)*8
  const int brow = tid >> 2;
  const int bk8  = (tid & 3) * 8;
  const f16* bp0 = xh + (size_t)brow * DF + bk8;
  const f16* bp1 = xh + (size_t)(brow + 128) * DF + bk8;

  f32x4 acc[8] = {};
  float sq = 0.f;
  f32x4 gaA, gaB;
  f16x8 gb0A, gb1A, gb0B, gb1B;

  auto gload = [&](int k0, f32x4& ga, f16x8& g0, f16x8& g1) {
    ga = *(const f32x4*)(ap + k0);
    g0 = *(const f16x8*)(bp0 + k0);
    g1 = *(const f16x8*)(bp1 + k0);
  };
  auto swrite = [&](int buf, f32x4& ga, f16x8& g0, f16x8& g1) {
    f16x4 h;
#pragma unroll
    for (int j = 0; j < 4; ++j) { h[j] = (f16)ga[j]; sq = fmaf(ga[j], ga[j], sq); }
    *(f16x4*)(&As[buf][arow * QPAD + ak4]) = h;
    *(f16x8*)(&Bs[buf][brow * QPAD + bk8]) = g0;
    *(f16x8*)(&Bs[buf][(brow + 128) * QPAD + bk8]) = g1;
  };
  auto compute = [&](int buf) {
    f16x8 af = *(const f16x8*)(&As[buf][(wr * 16 + l15) * QPAD + kg * 8]);
#pragma unroll
    for (int c = 0; c < 8; ++c) {
      f16x8 bf = *(const f16x8*)(&Bs[buf][(wb * 128 + c * 16 + l15) * QPAD + kg * 8]);
      acc[c] = __builtin_amdgcn_mfma_f32_16x16x32_f16(af, bf, acc[c], 0, 0, 0);
    }
  };

  gload(0, gaA, gb0A, gb1A);
  swrite(0, gaA, gb0A, gb1A);
  gload(32, gaB, gb0B, gb1B);
  __syncthreads();

  for (int ks = 0; ks < 96; ks += 2) {
    if (ks + 2 < 96) gload((ks + 2) * 32, gaA, gb0A, gb1A);   // 2 steps ahead
    compute(0);                                               // step ks
    swrite(1, gaB, gb0B, gb1B);                               // step ks+1 data
    __syncthreads();
    if (ks + 3 < 96) gload((ks + 3) * 32, gaB, gb0B, gb1B);
    compute(1);                                               // step ks+1
    if (ks + 2 < 96) swrite(0, gaA, gb0A, gb1A);              // step ks+2 data
    __syncthreads();
  }

  // |d|^2 reduce across the 8 k-chunk threads of each row
  sq += __shfl_xor(sq, 1);
  sq += __shfl_xor(sq, 2);
  sq += __shfl_xor(sq, 4);
  if ((lane & 7) == 0) dn_s[wid * 8 + (lane >> 3)] = sq;
  __syncthreads();

  const float sg  = sigma[0];
  const float inv = 0.5f / (sg * sg);
  float pm[8], pl[8];
#pragma unroll
  for (int c = 0; c < 8; ++c) { pm[c] = -1e30f; pl[c] = 0.f; }

#pragma unroll
  for (int r = 0; r < 4; ++r) {
    const int trow = wr * 16 + kg * 4 + r;         // C/D: row=(l>>4)*4+reg
    const int row  = n0 + trow;
    const float dn = dn_s[trow];
    const bool ok  = row < NDATA;
    float* Sp = S + (size_t)row * BP + wb * 128 + l15;
#pragma unroll
    for (int c = 0; c < 8; ++c) {
      float v = ok ? (2.f * acc[c][r] - dn) * inv : -1e30f;
      Sp[c * 16] = v;
      pm[c] = fmaxf(pm[c], v);
    }
  }
#pragma unroll
  for (int r = 0; r < 4; ++r) {
    const int trow = wr * 16 + kg * 4 + r;
    const int row  = n0 + trow;
    const float dn = dn_s[trow];
    const bool ok  = row < NDATA;
#pragma unroll
    for (int c = 0; c < 8; ++c) {
      float v = ok ? (2.f * acc[c][r] - dn) * inv : -1e30f;
      pl[c] += __expf(v - pm[c]);                  // all-invalid: exp(0)*4, dies in merge
    }
  }

  // (m,l) tree: 16 slots per column, LDS reused from Bs
  float* redm = (float*)&Bs[0][0];   // 16 KB
  float* redl = (float*)&Bs[1][0];   // 16 KB
  const int slot = wr * 4 + kg;
#pragma unroll
  for (int c = 0; c < 8; ++c) {
    int col = wb * 128 + c * 16 + l15;
    redm[slot * 256 + col] = pm[c];
    redl[slot * 256 + col] = pl[c];
  }
  __syncthreads();
  if (tid < 256) {
    float m = -1e38f, l = 0.f;
#pragma unroll
    for (int s = 0; s < 16; ++s) {
      float m2 = redm[s * 256 + tid], l2 = redl[s * 256 + tid];
      if (m2 > m) { l = l * __expf(m - m2) + l2; m = m2; }
      else        { l += l2 * __expf(m2 - m); }
    }
    Mp[blockIdx.x * 256 + tid] = m;
    Lp[blockIdx.x * 256 + tid] = l;
  }
}

// ---------------- K3: combine partials -> M[b], L[b] (one 1024-thr block) ----------------
__global__ void k_comb(const float* __restrict__ Mp, const float* __restrict__ Lp,
                       float* __restrict__ M, float* __restrict__ L, int ngrp) {
  __shared__ float ms[4][256], ls[4][256];
  const int tid = threadIdx.x;
  const int q = tid >> 8, b = tid & 255;
  float m = -1e38f, l = 0.f;
  for (int g = q; g < ngrp; g += 4) {
    float m2 = Mp[g * 256 + b], l2 = Lp[g * 256 + b];
    if (m2 > m) { l = l * __expf(m - m2) + l2; m = m2; }
    else        { l += l2 * __expf(m2 - m); }
  }
  ms[q][b] = m; ls[q][b] = l;
  __syncthreads();
  if (q == 0) {
#pragma unroll
    for (int j = 1; j < 4; ++j) {
      float m2 = ms[j][b], l2 = ls[j][b];
      if (m2 > m) { l = l * __expf(m - m2) + l2; m = m2; }
      else        { l += l2 * __expf(m2 - m); }
    }
    M[b] = m; L[b] = l;
  }
}

// ---------------- K4: W[b][n] = exp(S - M_b) as fp16 (transposed layout) ----------------
__global__ void k_wfin(const float* __restrict__ S, const float* __restrict__ M,
                       f16* __restrict__ W) {
  const int tid = threadIdx.x;
  const int n0 = blockIdx.x * 64;
  const float mb = M[tid];
  f16* wp = W + (size_t)tid * NLD2 + n0;
#pragma unroll
  for (int q = 0; q < 8; ++q) {
    f16x8 w8;
#pragma unroll
    for (int j = 0; j < 8; ++j) {
      int n = n0 + q * 8 + j;
      float s = (n < NLD1) ? S[(size_t)n * BP + tid] : -1e30f;  // coalesced across tid
      w8[j] = (f16)__expf(s - mb);
    }
    *(f16x8*)(wp + q * 8) = w8;
  }
}

// ---------------- K5: eps partials = W @ data (split-K over n, runtime nch) ----------------
// 512 thr (8 waves), tile 256b x 128d, K-step 32 n. 2-deep prefetch of data AND W.
__global__ __launch_bounds__(512, 4) void k_pv(const float* __restrict__ data,
                                               const f16* __restrict__ W,
                                               float* __restrict__ part,
                                               int chn, int per8) {
  __shared__ f16 T[2][128 * 40];
  const int tid = threadIdx.x;
  const int wid = tid >> 6, lane = tid & 63;
  const int l15 = lane & 15, kg = lane >> 4;
  const int bid = blockIdx.x;
  const int swz = (bid & 7) * per8 + (bid >> 3);   // XCD-chunked (grid % 8 == 0)
  const int chunk = swz / NDT;
  const int dt = swz % NDT;
  const int d0 = dt * 128;
  const int nstart = chunk * chn;
  const int kst = chn >> 5;
  const int nl = tid >> 4, dl = (tid & 15) * 8;    // staging: 32 n-rows x 16 thr

  f32x4 acc[2][8] = {};

  const f16* wp0 = W + (size_t)((wid * 2 + 0) * 16 + l15) * NLD2 + nstart + kg * 8;
  const f16* wp1 = W + (size_t)((wid * 2 + 1) * 16 + l15) * NLD2 + nstart + kg * 8;

  f32x4 g0A, g1A, g0B, g1B;
  f16x8 w0A, w1A, w0B, w1B;

  auto gload = [&](int ks, f32x4& g0, f32x4& g1) {
    int row = nstart + ks * 32 + nl;
    int rc = row < NDATA ? row : NDATA - 1;        // tail rows have W==0
    const float* gp = data + (size_t)rc * DF + d0 + dl;
    g0 = *(const f32x4*)gp;
    g1 = *(const f32x4*)(gp + 4);
  };
  auto wload = [&](int ks, f16x8& w0, f16x8& w1) {
    w0 = *(const f16x8*)(wp0 + ks * 32);
    w1 = *(const f16x8*)(wp1 + ks * 32);
  };
  auto twrite = [&](int buf, f32x4& g0, f32x4& g1) {
#pragma unroll
    for (int j = 0; j < 8; ++j) {
      float v = (j < 4) ? g0[j] : g1[j - 4];
      int d = dl + j;
      int pn = nl ^ (((d >> 3) & 3) << 3);         // bank swizzle
      T[buf][d * 40 + pn] = (f16)v;
    }
  };
  auto compute = [&](int buf, f16x8& a0, f16x8& a1) {
#pragma unroll
    for (int c = 0; c < 8; ++c) {
      int d = c * 16 + l15;
      int pb = (kg * 8) ^ (((d >> 3) & 3) << 3);
      f16x8 bf = *(const f16x8*)(&T[buf][d * 40 + pb]);
      acc[0][c] = __builtin_amdgcn_mfma_f32_16x16x32_f16(a0, bf, acc[0][c], 0, 0, 0);
      acc[1][c] = __builtin_amdgcn_mfma_f32_16x16x32_f16(a1, bf, acc[1][c], 0, 0, 0);
    }
  };

  gload(0, g0A, g1A);
  twrite(0, g0A, g1A);
  wload(0, w0A, w1A);
  gload(1, g0B, g1B);
  wload(1, w0B, w1B);
  __syncthreads();

  for (int ks = 0; ks < kst; ks += 2) {
    if (ks + 2 < kst) gload(ks + 2, g0A, g1A);     // data 2 ahead, before MFMA
    compute(0, w0A, w1A);                          // step ks
    if (ks + 2 < kst) wload(ks + 2, w0A, w1A);     // W 2 ahead, after its consumer
    twrite(1, g0B, g1B);                           // step ks+1 data
    __syncthreads();
    if (ks + 3 < kst) gload(ks + 3, g0B, g1B);
    compute(1, w0B, w1B);                          // step ks+1
    if (ks + 3 < kst) wload(ks + 3, w0B, w1B);
    if (ks + 2 < kst) twrite(0, g0A, g1A);         // step ks+2 data
    __syncthreads();
  }

  float* pp = part + (size_t)chunk * (BP * DF);
#pragma unroll
  for (int i = 0; i < 2; ++i)
#pragma unroll
    for (int c = 0; c < 8; ++c)
#pragma unroll
      for (int r = 0; r < 4; ++r) {
        int b = (wid * 2 + i) * 16 + kg * 4 + r;
        int d = d0 + c * 16 + l15;
        pp[(size_t)b * DF + d] = acc[i][c][r];
      }
}

// ---------------- K6: out = (x - (sum partials)/L) / sigma ----------------
__global__ void k_final(const float* __restrict__ x, const float* __restrict__ sigma,
                        const float* __restrict__ part, const float* __restrict__ L,
                        float* __restrict__ out, int nch) {
  int i = blockIdx.x * 256 + threadIdx.x;   // float4 index
  int b = (i * 4) / DF;
  f32x4 s = {};
  for (int c = 0; c < nch; ++c) s += ((const f32x4*)(part + (size_t)c * BP * DF))[i];
  f32x4 xv = ((const f32x4*)x)[i];
  float invL = 1.f / L[b];
  float sg = sigma[0];
  float invsg = 1.f / sg;
  f32x4 r;
#pragma unroll
  for (int j = 0; j < 4; ++j) r[j] = (xv[j] - s[j] * invL) * invsg;
  ((f32x4*)out)[i] = r;
}

extern "C" void kernel_launch(void* const* d_in, const int* in_sizes, int n_in,
                              void* d_out, int out_size, void* d_ws, size_t ws_size,
                              hipStream_t stream) {
  const float* x     = (const float*)d_in[0];
  const float* sigma = (const float*)d_in[1];
  const float* data  = (const float*)d_in[2];
  float* out = (float*)d_out;
  char* ws = (char*)d_ws;

  float* S  = (float*)(ws + OFF_S);
  f16*   W  = (f16*)(ws + OFF_W);
  f16*   xh = (f16*)(ws + OFF_XH);
  float* Mp = (float*)(ws + OFF_MP);
  float* Lp = (float*)(ws + OFF_LP);
  float* M  = (float*)(ws + OFF_M);
  float* L  = (float*)(ws + OFF_L);
  float* P  = (float*)(ws + OFF_P);

  // split-K width chosen by available workspace (grid balance: 576 -> 2.25 blk/CU)
  int nch = 24, chn = 2112;
  if (ws_size < OFF_P + 24 * SLAB) { nch = 16; chn = 3200; }
  if (ws_size < OFF_P + 16 * SLAB) { nch = 8;  chn = 6400; }
  const int grid_pv = NDT * nch;
  const int per8 = grid_pv / 8;

  k_prep_x<<<768, 256, 0, stream>>>(x, xh);
  k_qk<<<NGRP, 512, 0, stream>>>(data, xh, sigma, S, Mp, Lp);
  k_comb<<<1, 1024, 0, stream>>>(Mp, Lp, M, L, NGRP);
  k_wfin<<<NLD2 / 64, 256, 0, stream>>>(S, M, W);
  k_pv<<<grid_pv, 512, 0, stream>>>(data, W, P, chn, per8);
  k_final<<<768, 256, 0, stream>>>(x, sigma, P, L, out, nch);
}